// Round 1
// baseline (378.028 us; speedup 1.0000x reference)
//
#include <hip/hip_runtime.h>
#include <hip/hip_bf16.h>

// Problem shape (fixed by reference setup_inputs): M = B*S = 8192, K = NX = 1024, N = NF = 4096
#define M_DIM 8192
#define K_DIM 1024
#define N_DIM 4096
#define BM 128
#define BN 128

typedef __attribute__((ext_vector_type(8))) short bf16x8;
typedef __attribute__((ext_vector_type(4))) float f32x4;

// f32 -> bf16 round-to-nearest-even (bit-exact for the integer/2^k values we feed it)
__device__ __forceinline__ short f2bf(float f) {
  unsigned u = __builtin_bit_cast(unsigned, f);
  u = (u + 0x7fffu + ((u >> 16) & 1u)) >> 16;
  return (short)u;
}

__device__ __forceinline__ float gelu_f(float x) {
  // 0.5*x*(1+tanh(c*(x + 0.044715 x^3))), tanh via exp (graceful at +/-inf)
  float u = 0.7978845608028654f * (x + 0.044715f * x * x * x);
  float e = __expf(2.0f * u);
  float t = 1.0f - 2.0f / (e + 1.0f);
  return 0.5f * x * (1.0f + t);
}

__device__ __forceinline__ void gload16(const void* g, void* l) {
  __builtin_amdgcn_global_load_lds((const __attribute__((address_space(1))) void*)g,
                                   (__attribute__((address_space(3))) void*)l, 16, 0, 0);
}

// ---------------- prep: per-row power-of-2 weight scale ----------------
// mw[r] = 2^rint(log2(max_j |W[r,j]|)), one wave per row
__global__ void rowmax_kernel(const float* __restrict__ w, float* __restrict__ mw) {
  int row = blockIdx.x * 4 + (threadIdx.x >> 6);
  int lane = threadIdx.x & 63;
  const float4* rp = (const float4*)(w + (size_t)row * N_DIM);
  float m = 0.0f;
#pragma unroll
  for (int it = 0; it < 16; ++it) {
    float4 v = rp[it * 64 + lane];
    m = fmaxf(m, fmaxf(fmaxf(fabsf(v.x), fabsf(v.y)), fmaxf(fabsf(v.z), fabsf(v.w))));
  }
#pragma unroll
  for (int off = 32; off > 0; off >>= 1) m = fmaxf(m, __shfl_xor(m, off, 64));
  if (lane == 0) mw[row] = exp2f(rintf(log2f(m)));
}

// ---------------- prep A: quantize input, pack k-chunk-major [K/8][M][8] bf16 ----------------
// chunk c = kg*M + m ; thread reads 8 consecutive f32 of row m, writes 16B chunk to each of 3 bufs
__global__ void prep_a_kernel(const float* __restrict__ inp, short* __restrict__ aq,
                              short* __restrict__ ad, short* __restrict__ af) {
  int c = blockIdx.x * 256 + threadIdx.x;   // 128*8192 = 1,048,576 chunks
  int kg = c >> 13;                          // c / 8192
  int m = c & 8191;
  const float* src = inp + (size_t)m * K_DIM + kg * 8;
  float4 x0 = *(const float4*)src;
  float4 x1 = *(const float4*)(src + 4);
  float xs[8] = {x0.x, x0.y, x0.z, x0.w, x1.x, x1.y, x1.z, x1.w};
  bf16x8 vq, vd, vf;
#pragma unroll
  for (int j = 0; j < 8; ++j) {
    float x = xs[j];
    float s = (float)((x > 0.0f) - (x < 0.0f));
    float r = rintf(fabsf(x));               // |x|/8*8 == |x| exactly; rint = round-half-even
    vq[j] = f2bf(s * fminf(r + 1.0f, 7.0f)); // in_q
    vd[j] = f2bf(s * fminf(r, 6.0f));        // reverse_signed_quant(in_q) = sign*min(rint|x|,6)
    vf[j] = f2bf(x);                         // full-precision path operand (bf16 RNE)
  }
  *(bf16x8*)(aq + (size_t)c * 8) = vq;
  *(bf16x8*)(ad + (size_t)c * 8) = vd;
  *(bf16x8*)(af + (size_t)c * 8) = vf;
}

// ---------------- prep W: quantize weight, pack transposed k-chunk-major [K/8][N][8] bf16 ------
__global__ void prep_w_kernel(const float* __restrict__ w, const float* __restrict__ mw,
                              short* __restrict__ wq, short* __restrict__ wd,
                              short* __restrict__ wf) {
  int c = blockIdx.x * 256 + threadIdx.x;   // 128*4096 = 524,288 chunks
  int kg = c >> 12;                          // c / 4096
  int n = c & 4095;
  bf16x8 vq, vd, vf;
#pragma unroll
  for (int j = 0; j < 8; ++j) {
    float wv = w[(size_t)(kg * 8 + j) * N_DIM + n];  // coalesced across threads (n fastest)
    float sc = mw[kg * 8 + j];                       // wave-uniform
    float s = (float)((wv > 0.0f) - (wv < 0.0f));
    float r = rintf(fabsf(wv) / sc * 8.0f);          // /2^k*8 exact
    vq[j] = f2bf(s * fminf(r + 1.0f, 7.0f));                  // w_q (integer)
    vd[j] = f2bf(s * fminf(r, 6.0f) * 0.125f * sc);           // deq(w_q) = int * mw/8 (exact bf16)
    vf[j] = f2bf(wv);
  }
  *(bf16x8*)(wq + (size_t)c * 8) = vq;
  *(bf16x8*)(wd + (size_t)c * 8) = vd;
  *(bf16x8*)(wf + (size_t)c * 8) = vf;
}

// ---------------- fused triple GEMM + select + GELU ----------------
// 128x128 tile, BK=32, 512 thr (8 waves 2x4), per-wave 64x32, 3 accumulator sets.
// LDS: 6 panels of 512 chunks x 16B (A-panels [k2:4][m:128][8], B-panels [k2:4][n:128][8]) = 48KB
__global__ __launch_bounds__(512) void fused_gemm_kernel(
    const short* __restrict__ aq, const short* __restrict__ ad, const short* __restrict__ af,
    const short* __restrict__ wq, const short* __restrict__ wd, const short* __restrict__ wf,
    const float* __restrict__ bias, float* __restrict__ out) {
  __shared__ short lds[6][4096];

  int tid = threadIdx.x;
  int wid = tid >> 6;
  int lane = tid & 63;

  // XCD-aware swizzle: 2048 blocks, 8 XCDs -> 256 contiguous tiles per XCD (bijective)
  int bid = blockIdx.x;
  bid = (bid & 7) * 256 + (bid >> 3);
  int bm0 = (bid >> 5) * BM;   // 64 m-tiles
  int bn0 = (bid & 31) * BN;   // 32 n-tiles

  int wr = wid >> 2;           // 0..1  -> 64 rows each
  int wc = wid & 3;            // 0..3  -> 32 cols each

  f32x4 acc[3][4][2];
#pragma unroll
  for (int q = 0; q < 3; ++q)
#pragma unroll
    for (int mf = 0; mf < 4; ++mf)
#pragma unroll
      for (int nf = 0; nf < 2; ++nf) acc[q][mf][nf] = (f32x4){0.f, 0.f, 0.f, 0.f};

  // staging geometry: per k-step each thread issues 6 global_load_lds (one per panel),
  // instruction slot t = wid; global chunk = (kc0 + t>>1)*stride + base + (t&1)*64 + lane
  const int k2s = wid >> 1;
  const int half64 = (wid & 1) << 6;
  // fragment LDS offsets (constant across k-loop); chunk = (lane>>4)*128 + rowcol
  const int k2r = (lane >> 4) << 7;
  const int rl = lane & 15;
  const int aoff = (k2r + wr * 64 + rl) * 8;
  const int boff = (k2r + wc * 32 + rl) * 8;

  for (int kt = 0; kt < 32; ++kt) {
    int kc0 = kt << 2;
    {
      int ca = ((kc0 + k2s) << 13) + bm0 + half64 + lane;  // *M_DIM
      int cb = ((kc0 + k2s) << 12) + bn0 + half64 + lane;  // *N_DIM
      void* la = (void*)&lds[0][wid * 512];
      gload16(aq + (size_t)ca * 8, la);
      gload16(ad + (size_t)ca * 8, (void*)&lds[1][wid * 512]);
      gload16(af + (size_t)ca * 8, (void*)&lds[2][wid * 512]);
      gload16(wq + (size_t)cb * 8, (void*)&lds[3][wid * 512]);
      gload16(wd + (size_t)cb * 8, (void*)&lds[4][wid * 512]);
      gload16(wf + (size_t)cb * 8, (void*)&lds[5][wid * 512]);
    }
    __syncthreads();  // compiler drains vmcnt(0) before s_barrier -> LDS tile ready

    bf16x8 aF[3][4], bF[3][2];
#pragma unroll
    for (int q = 0; q < 3; ++q)
#pragma unroll
      for (int mf = 0; mf < 4; ++mf)
        aF[q][mf] = *(const bf16x8*)&lds[q][aoff + mf * 128];
#pragma unroll
    for (int q = 0; q < 3; ++q)
#pragma unroll
      for (int nf = 0; nf < 2; ++nf)
        bF[q][nf] = *(const bf16x8*)&lds[3 + q][boff + nf * 128];

#pragma unroll
    for (int q = 0; q < 3; ++q)
#pragma unroll
      for (int mf = 0; mf < 4; ++mf)
#pragma unroll
        for (int nf = 0; nf < 2; ++nf)
          acc[q][mf][nf] = __builtin_amdgcn_mfma_f32_16x16x32_bf16(
              aF[q][mf], bF[q][nf], acc[q][mf][nf], 0, 0, 0);
    __syncthreads();  // everyone done reading before next tile overwrites LDS
  }

  // epilogue: select by exact integer sign, add (quantized) bias, GELU, store
#pragma unroll
  for (int nf = 0; nf < 2; ++nf) {
    int col = bn0 + wc * 32 + nf * 16 + rl;
    float b = bias[col];
    float sb = (float)((b > 0.0f) - (b < 0.0f));
    float db = sb * fminf(rintf(fabsf(b)), 6.0f);  // reverse(signed_quant(bias)) for mv=8,n=8
#pragma unroll
    for (int mf = 0; mf < 4; ++mf) {
#pragma unroll
      for (int i = 0; i < 4; ++i) {
        int row = bm0 + wr * 64 + mf * 16 + (lane >> 4) * 4 + i;
        float s1 = acc[0][mf][nf][i];  // exact integer
        float v = (s1 < 0.0f) ? (acc[1][mf][nf][i] + db) : (acc[2][mf][nf][i] + b);
        out[(size_t)row * N_DIM + col] = gelu_f(v);
      }
    }
  }
}

extern "C" void kernel_launch(void* const* d_in, const int* in_sizes, int n_in,
                              void* d_out, int out_size, void* d_ws, size_t ws_size,
                              hipStream_t stream) {
  const float* inp = (const float*)d_in[0];
  const float* w = (const float*)d_in[1];
  const float* bias = (const float*)d_in[2];
  float* out = (float*)d_out;

  // workspace layout (75.5 MB total):
  //   Aq/Ad/Af: 3 x 8192*1024 bf16 (16.78 MB each), Wq/Wd/Wf: 3 x 1024*4096 bf16 (8.39 MB each),
  //   mw: 1024 f32
  short* aq = (short*)d_ws;
  short* ad = aq + (size_t)M_DIM * K_DIM;
  short* af = ad + (size_t)M_DIM * K_DIM;
  short* wq = af + (size_t)M_DIM * K_DIM;
  short* wd = wq + (size_t)K_DIM * N_DIM;
  short* wf = wd + (size_t)K_DIM * N_DIM;
  float* mw = (float*)(wf + (size_t)K_DIM * N_DIM);

  rowmax_kernel<<<K_DIM / 4, 256, 0, stream>>>(w, mw);
  prep_a_kernel<<<(M_DIM / 8) * (K_DIM / 256), 256, 0, stream>>>(inp, aq, ad, af);
  prep_w_kernel<<<(N_DIM / 8) * (K_DIM / 256), 256, 0, stream>>>(w, mw, wq, wd, wf);
  fused_gemm_kernel<<<(M_DIM / BM) * (N_DIM / BN), 512, 0, stream>>>(aq, ad, af, wq, wd, wf,
                                                                     bias, out);
}

// Round 2
// 302.448 us; speedup vs baseline: 1.2499x; 1.2499x over previous
//
#include <hip/hip_runtime.h>
#include <hip/hip_bf16.h>

// Problem shape (fixed by reference setup_inputs): M = B*S = 8192, K = NX = 1024, N = NF = 4096
#define M_DIM 8192
#define K_DIM 1024
#define N_DIM 4096
#define BM 128
#define BN 64

typedef __attribute__((ext_vector_type(8))) short bf16x8;
typedef __attribute__((ext_vector_type(4))) float f32x4;

// f32 -> bf16 round-to-nearest-even (bit-exact for the integer/2^k values we feed it)
__device__ __forceinline__ short f2bf(float f) {
  unsigned u = __builtin_bit_cast(unsigned, f);
  u = (u + 0x7fffu + ((u >> 16) & 1u)) >> 16;
  return (short)u;
}

__device__ __forceinline__ float gelu_f(float x) {
  float u = 0.7978845608028654f * (x + 0.044715f * x * x * x);
  float e = __expf(2.0f * u);
  float t = 1.0f - 2.0f / (e + 1.0f);
  return 0.5f * x * (1.0f + t);
}

__device__ __forceinline__ void gload16(const void* g, void* l) {
  __builtin_amdgcn_global_load_lds((const __attribute__((address_space(1))) void*)g,
                                   (__attribute__((address_space(3))) void*)l, 16, 0, 0);
}

// ---------------- prep: per-row power-of-2 weight scale ----------------
__global__ void rowmax_kernel(const float* __restrict__ w, float* __restrict__ mw) {
  int row = blockIdx.x * 4 + (threadIdx.x >> 6);
  int lane = threadIdx.x & 63;
  const float4* rp = (const float4*)(w + (size_t)row * N_DIM);
  float m = 0.0f;
#pragma unroll
  for (int it = 0; it < 16; ++it) {
    float4 v = rp[it * 64 + lane];
    m = fmaxf(m, fmaxf(fmaxf(fabsf(v.x), fabsf(v.y)), fmaxf(fabsf(v.z), fabsf(v.w))));
  }
#pragma unroll
  for (int off = 32; off > 0; off >>= 1) m = fmaxf(m, __shfl_xor(m, off, 64));
  if (lane == 0) mw[row] = exp2f(rintf(log2f(m)));
}

// ---------------- prep A: quantize input, pack k-chunk-major [K/8][M][8] bf16 ----------------
__global__ void prep_a_kernel(const float* __restrict__ inp, short* __restrict__ aq,
                              short* __restrict__ ad, short* __restrict__ af) {
  int c = blockIdx.x * 256 + threadIdx.x;   // 1,048,576 chunks
  int kg = c >> 13;
  int m = c & 8191;
  const float* src = inp + (size_t)m * K_DIM + kg * 8;
  float4 x0 = *(const float4*)src;
  float4 x1 = *(const float4*)(src + 4);
  float xs[8] = {x0.x, x0.y, x0.z, x0.w, x1.x, x1.y, x1.z, x1.w};
  bf16x8 vq, vd, vf;
#pragma unroll
  for (int j = 0; j < 8; ++j) {
    float x = xs[j];
    float s = (float)((x > 0.0f) - (x < 0.0f));
    float r = rintf(fabsf(x));
    vq[j] = f2bf(s * fminf(r + 1.0f, 7.0f));
    vd[j] = f2bf(s * fminf(r, 6.0f));
    vf[j] = f2bf(x);
  }
  *(bf16x8*)(aq + (size_t)c * 8) = vq;
  *(bf16x8*)(ad + (size_t)c * 8) = vd;
  *(bf16x8*)(af + (size_t)c * 8) = vf;
}

// ---------------- prep W: quantize weight, pack transposed k-chunk-major [K/8][N][8] bf16 ------
__global__ void prep_w_kernel(const float* __restrict__ w, const float* __restrict__ mw,
                              short* __restrict__ wq, short* __restrict__ wd,
                              short* __restrict__ wf) {
  int c = blockIdx.x * 256 + threadIdx.x;   // 524,288 chunks
  int kg = c >> 12;
  int n = c & 4095;
  bf16x8 vq, vd, vf;
#pragma unroll
  for (int j = 0; j < 8; ++j) {
    float wv = w[(size_t)(kg * 8 + j) * N_DIM + n];
    float sc = mw[kg * 8 + j];
    float s = (float)((wv > 0.0f) - (wv < 0.0f));
    float r = rintf(fabsf(wv) / sc * 8.0f);
    vq[j] = f2bf(s * fminf(r + 1.0f, 7.0f));
    vd[j] = f2bf(s * fminf(r, 6.0f) * 0.125f * sc);
    vf[j] = f2bf(wv);
  }
  *(bf16x8*)(wq + (size_t)c * 8) = vq;
  *(bf16x8*)(wd + (size_t)c * 8) = vd;
  *(bf16x8*)(wf + (size_t)c * 8) = vf;
}

// ---------------- fused triple GEMM + select + GELU ----------------
// 128x64 tile, BK=32, 256 thr (4 waves 2x2), per-wave 64x32, 3 accumulator sets.
// LDS single-buffered 36KB: A panels 3x[4kg][128m][8], B panels 3x[4kg][64n][8].
// Target: <=170 VGPR -> 3 blocks/CU resident (12 waves) for latency hiding.
__global__ __launch_bounds__(256, 3) void fused_gemm_kernel(
    const short* __restrict__ aq, const short* __restrict__ ad, const short* __restrict__ af,
    const short* __restrict__ wq, const short* __restrict__ wd, const short* __restrict__ wf,
    const float* __restrict__ bias, float* __restrict__ out) {
  __shared__ short lds[2304 * 8];  // 2304 chunks x 16B = 36 KB

  int tid = threadIdx.x;
  int wid = tid >> 6;   // 0..3
  int lane = tid & 63;

  // XCD-aware swizzle: 4096 blocks, 8 XCDs -> 512 contiguous tiles per XCD (bijective)
  int bid = blockIdx.x;
  bid = (bid & 7) * 512 + (bid >> 3);
  int bm0 = (bid >> 6) * BM;   // 64 m-tiles
  int bn0 = (bid & 63) * BN;   // 64 n-tiles

  int wr = wid >> 1;           // 0..1 -> 64 rows each
  int wc = wid & 1;            // 0..1 -> 32 cols each

  f32x4 acc[3][4][2];
#pragma unroll
  for (int q = 0; q < 3; ++q)
#pragma unroll
    for (int mf = 0; mf < 4; ++mf)
#pragma unroll
      for (int nf = 0; nf < 2; ++nf) acc[q][mf][nf] = (f32x4){0.f, 0.f, 0.f, 0.f};

  // --- staging geometry (per K-step = 32 k = 4 k-groups of 8) ---
  // A panel: 512 chunks [kg:4][row:128]; thread slots j0=wid, j1=4+wid cover 64 chunks each
  const int j0 = wid, j1 = 4 + wid;
  const int kgA0 = j0 >> 1, rowA0 = (j0 & 1) * 64;   // + lane
  const int kgA1 = j1 >> 1, rowA1 = (j1 & 1) * 64;
  const int ldsA0 = j0 * 64 * 8;  // shorts, per-panel base added per q
  const int ldsA1 = j1 * 64 * 8;
  // B panel: 256 chunks [kg:4][n:64]; one slot: kg=wid, n=lane
  const int ldsB = (1536 + wid * 64) * 8;

  // --- fragment LDS offsets (shorts) ---
  const int g = lane >> 4, rl = lane & 15;
  const int aoff = (g * 128 + wr * 64 + rl) * 8;           // + q*512*8, + mf*16*8... (mf stride 128)
  const int boff = (1536 + g * 64 + wc * 32 + rl) * 8;     // + q*256*8, nf stride 128

  for (int kt = 0; kt < 32; ++kt) {
    int kc0 = kt << 2;
    {
      int ca0 = ((kc0 + kgA0) << 13) + bm0 + rowA0 + lane;
      int ca1 = ((kc0 + kgA1) << 13) + bm0 + rowA1 + lane;
      int cb = ((kc0 + wid) << 12) + bn0 + lane;
      gload16(aq + (size_t)ca0 * 8, (void*)&lds[0 * 4096 + ldsA0]);
      gload16(aq + (size_t)ca1 * 8, (void*)&lds[0 * 4096 + ldsA1]);
      gload16(ad + (size_t)ca0 * 8, (void*)&lds[1 * 4096 + ldsA0]);
      gload16(ad + (size_t)ca1 * 8, (void*)&lds[1 * 4096 + ldsA1]);
      gload16(af + (size_t)ca0 * 8, (void*)&lds[2 * 4096 + ldsA0]);
      gload16(af + (size_t)ca1 * 8, (void*)&lds[2 * 4096 + ldsA1]);
      gload16(wq + (size_t)cb * 8, (void*)&lds[ldsB + 0 * 2048]);
      gload16(wd + (size_t)cb * 8, (void*)&lds[ldsB + 1 * 2048]);
      gload16(wf + (size_t)cb * 8, (void*)&lds[ldsB + 2 * 2048]);
    }
    __syncthreads();  // vmcnt(0) drained before barrier -> tile ready

#pragma unroll
    for (int q = 0; q < 3; ++q) {
      bf16x8 aF[4], bF[2];
#pragma unroll
      for (int mf = 0; mf < 4; ++mf)
        aF[mf] = *(const bf16x8*)&lds[q * 4096 + aoff + mf * 128];
#pragma unroll
      for (int nf = 0; nf < 2; ++nf)
        bF[nf] = *(const bf16x8*)&lds[q * 2048 + boff + nf * 128];
#pragma unroll
      for (int mf = 0; mf < 4; ++mf)
#pragma unroll
        for (int nf = 0; nf < 2; ++nf)
          acc[q][mf][nf] = __builtin_amdgcn_mfma_f32_16x16x32_bf16(
              aF[mf], bF[nf], acc[q][mf][nf], 0, 0, 0);
    }
    __syncthreads();  // all reads done before next tile overwrites LDS
  }

  // epilogue: select by exact integer sign, add (quantized) bias, GELU, store
#pragma unroll
  for (int nf = 0; nf < 2; ++nf) {
    int col = bn0 + wc * 32 + nf * 16 + rl;
    float b = bias[col];
    float sb = (float)((b > 0.0f) - (b < 0.0f));
    float db = sb * fminf(rintf(fabsf(b)), 6.0f);
#pragma unroll
    for (int mf = 0; mf < 4; ++mf) {
#pragma unroll
      for (int i = 0; i < 4; ++i) {
        int row = bm0 + wr * 64 + mf * 16 + g * 4 + i;
        float s1 = acc[0][mf][nf][i];  // exact integer
        float v = (s1 < 0.0f) ? (acc[1][mf][nf][i] + db) : (acc[2][mf][nf][i] + b);
        out[(size_t)row * N_DIM + col] = gelu_f(v);
      }
    }
  }
}

extern "C" void kernel_launch(void* const* d_in, const int* in_sizes, int n_in,
                              void* d_out, int out_size, void* d_ws, size_t ws_size,
                              hipStream_t stream) {
  const float* inp = (const float*)d_in[0];
  const float* w = (const float*)d_in[1];
  const float* bias = (const float*)d_in[2];
  float* out = (float*)d_out;

  short* aq = (short*)d_ws;
  short* ad = aq + (size_t)M_DIM * K_DIM;
  short* af = ad + (size_t)M_DIM * K_DIM;
  short* wq = af + (size_t)M_DIM * K_DIM;
  short* wd = wq + (size_t)K_DIM * N_DIM;
  short* wf = wd + (size_t)K_DIM * N_DIM;
  float* mw = (float*)(wf + (size_t)K_DIM * N_DIM);

  rowmax_kernel<<<K_DIM / 4, 256, 0, stream>>>(w, mw);
  prep_a_kernel<<<(M_DIM / 8) * (K_DIM / 256), 256, 0, stream>>>(inp, aq, ad, af);
  prep_w_kernel<<<(N_DIM / 8) * (K_DIM / 256), 256, 0, stream>>>(w, mw, wq, wd, wf);
  fused_gemm_kernel<<<(M_DIM / BM) * (N_DIM / BN), 256, 0, stream>>>(aq, ad, af, wq, wd, wf,
                                                                     bias, out);
}